// Round 3
// baseline (908.259 us; speedup 1.0000x reference)
//
#include <hip/hip_runtime.h>

// Problem constants (B,S,D,H fixed by reference)
constexpr int Bn = 32, Sn = 512, Dn = 512, Hn = 8, DKn = 64;

typedef __attribute__((ext_vector_type(8))) short bf16x8;
typedef __attribute__((ext_vector_type(8))) _Float16 f16x8;
typedef __attribute__((ext_vector_type(4))) _Float16 f16x4;
typedef __attribute__((ext_vector_type(4))) float f32x4;

#define DEV_INLINE __device__ __forceinline__

DEV_INLINE float bf2f(unsigned int u) { return __uint_as_float(u << 16); }

DEV_INLINE unsigned short f2bf(float f) {
  unsigned int u = __float_as_uint(f);
  u += 0x7fffu + ((u >> 16) & 1u);   // round-to-nearest-even; inputs finite
  return (unsigned short)(u >> 16);
}

DEV_INLINE void unpack8(const uint4 r, float* o) {
  o[0] = bf2f(r.x & 0xffffu); o[1] = bf2f(r.x >> 16);
  o[2] = bf2f(r.y & 0xffffu); o[3] = bf2f(r.y >> 16);
  o[4] = bf2f(r.z & 0xffffu); o[5] = bf2f(r.z >> 16);
  o[6] = bf2f(r.w & 0xffffu); o[7] = bf2f(r.w >> 16);
}

struct F16Pair { _Float16 hi, lo; };
DEV_INLINE F16Pair splitf(float x) {
  F16Pair p;
  p.hi = (_Float16)x;
  p.lo = (_Float16)(x - (float)p.hi);
  return p;
}

// ---------------------------------------------------------------------------
// fp32-accurate GEMM via f16x2 split MFMA (Markidis): out = A[M,512]*W + b.
// W pre-scaled by 64 at staging so its lo-half stays f16-normal; epilogue
// rescales by 1/64. Output: fp32 heads layout [b,h,s,dk].
// Error vs fp32 numpy ~2e-7 relative — needed for top-k selection stability.
// ---------------------------------------------------------------------------
__global__ __launch_bounds__(256) void gemm_f16split_kernel(
    const float* __restrict__ A, const float* __restrict__ W,
    const float* __restrict__ bias, float* __restrict__ outh) {
  __shared__ _Float16 Ash[128][48], Asl[128][48];
  __shared__ _Float16 Bsh[128][48], Bsl[128][48];  // [n][k] transposed

  const int m0 = blockIdx.x * 128, n0 = blockIdx.y * 128;
  const int tid  = threadIdx.x;
  const int lane = tid & 63, wave = tid >> 6;
  const int waveM = wave >> 1, waveN = wave & 1;
  const int col = lane & 15, quad = lane >> 4;

  f32x4 acc[4][4];
#pragma unroll
  for (int mi = 0; mi < 4; ++mi)
#pragma unroll
    for (int ni = 0; ni < 4; ++ni) acc[mi][ni] = (f32x4){0.f, 0.f, 0.f, 0.f};

  for (int k0 = 0; k0 < 512; k0 += 32) {
    __syncthreads();
#pragma unroll
    for (int it = 0; it < 4; ++it) {
      int chunk = tid + it * 256;            // 1024 float4 chunks (128x32)
      int r = chunk >> 3, c4 = chunk & 7;
      float4 v = *(const float4*)(A + (long)(m0 + r) * 512 + k0 + c4 * 4);
      F16Pair p0 = splitf(v.x), p1 = splitf(v.y),
              p2 = splitf(v.z), p3 = splitf(v.w);
      f16x4 hv = {p0.hi, p1.hi, p2.hi, p3.hi};
      f16x4 lv = {p0.lo, p1.lo, p2.lo, p3.lo};
      *(f16x4*)&Ash[r][c4 * 4] = hv;
      *(f16x4*)&Asl[r][c4 * 4] = lv;
    }
    // W [K,N] fp32 -> Bs[n][k] f16 hi/lo (transposed), scaled by 64
#pragma unroll
    for (int it = 0; it < 4; ++it) {
      int chunk = tid + it * 256;            // 32 k-rows x 32 n-chunks
      int r = chunk >> 5, c4 = chunk & 31;
      float4 v = *(const float4*)(W + (long)(k0 + r) * 512 + n0 + c4 * 4);
      F16Pair p0 = splitf(v.x * 64.f), p1 = splitf(v.y * 64.f),
              p2 = splitf(v.z * 64.f), p3 = splitf(v.w * 64.f);
      Bsh[c4 * 4 + 0][r] = p0.hi; Bsl[c4 * 4 + 0][r] = p0.lo;
      Bsh[c4 * 4 + 1][r] = p1.hi; Bsl[c4 * 4 + 1][r] = p1.lo;
      Bsh[c4 * 4 + 2][r] = p2.hi; Bsl[c4 * 4 + 2][r] = p2.lo;
      Bsh[c4 * 4 + 3][r] = p3.hi; Bsl[c4 * 4 + 3][r] = p3.lo;
    }
    __syncthreads();

    f16x8 ah[4], al[4], bh[4], bl[4];
#pragma unroll
    for (int mi = 0; mi < 4; ++mi) {
      ah[mi] = *(const f16x8*)&Ash[waveM * 64 + mi * 16 + col][quad * 8];
      al[mi] = *(const f16x8*)&Asl[waveM * 64 + mi * 16 + col][quad * 8];
    }
#pragma unroll
    for (int ni = 0; ni < 4; ++ni) {
      bh[ni] = *(const f16x8*)&Bsh[waveN * 64 + ni * 16 + col][quad * 8];
      bl[ni] = *(const f16x8*)&Bsl[waveN * 64 + ni * 16 + col][quad * 8];
    }
#pragma unroll
    for (int mi = 0; mi < 4; ++mi)
#pragma unroll
      for (int ni = 0; ni < 4; ++ni) {
        acc[mi][ni] = __builtin_amdgcn_mfma_f32_16x16x32_f16(
            ah[mi], bl[ni], acc[mi][ni], 0, 0, 0);
        acc[mi][ni] = __builtin_amdgcn_mfma_f32_16x16x32_f16(
            al[mi], bh[ni], acc[mi][ni], 0, 0, 0);
        acc[mi][ni] = __builtin_amdgcn_mfma_f32_16x16x32_f16(
            ah[mi], bh[ni], acc[mi][ni], 0, 0, 0);
      }
  }

  // C/D layout: col=lane&15, row=quad*4+reg (m89/m91-verified)
#pragma unroll
  for (int ni = 0; ni < 4; ++ni) {
    const int gn = n0 + waveN * 64 + ni * 16 + col;
    const float bv = bias[gn];
    const int h_ = gn >> 6, dk_ = gn & 63;
#pragma unroll
    for (int mi = 0; mi < 4; ++mi) {
#pragma unroll
      for (int r = 0; r < 4; ++r) {
        const int gm = m0 + waveM * 64 + mi * 16 + quad * 4 + r;
        const int b_ = gm >> 9, s_ = gm & 511;
        outh[(((long)(b_ * 8 + h_)) * 512 + s_) * 64 + dk_] =
            acc[mi][ni][r] * 0.015625f + bv;
      }
    }
  }
}

// ---------------------------------------------------------------------------
// bf16 MFMA GEMM (for v-projection and out-projection; continuous-error path)
// ---------------------------------------------------------------------------
template <bool A_IS_BF16, bool HEADS_OUT>
__global__ __launch_bounds__(256) void gemm_kernel(
    const void* __restrict__ Av, const float* __restrict__ W,
    const float* __restrict__ bias, void* __restrict__ outv) {
  __shared__ unsigned short As[128][48];
  __shared__ unsigned short Bs[128][48];  // [n][k]

  const int m0 = blockIdx.x * 128, n0 = blockIdx.y * 128;
  const int tid  = threadIdx.x;
  const int lane = tid & 63, wave = tid >> 6;
  const int waveM = wave >> 1, waveN = wave & 1;
  const int col = lane & 15, quad = lane >> 4;

  f32x4 acc[4][4];
#pragma unroll
  for (int mi = 0; mi < 4; ++mi)
#pragma unroll
    for (int ni = 0; ni < 4; ++ni) acc[mi][ni] = (f32x4){0.f, 0.f, 0.f, 0.f};

  for (int k0 = 0; k0 < 512; k0 += 32) {
    __syncthreads();
    if constexpr (!A_IS_BF16) {
      const float* A = (const float*)Av;
#pragma unroll
      for (int it = 0; it < 4; ++it) {
        int chunk = tid + it * 256;
        int r = chunk >> 3, c4 = chunk & 7;
        float4 v = *(const float4*)(A + (long)(m0 + r) * 512 + k0 + c4 * 4);
        ushort4 w;
        w.x = f2bf(v.x); w.y = f2bf(v.y); w.z = f2bf(v.z); w.w = f2bf(v.w);
        *(ushort4*)&As[r][c4 * 4] = w;
      }
    } else {
      const unsigned short* A = (const unsigned short*)Av;
#pragma unroll
      for (int it = 0; it < 2; ++it) {
        int chunk = tid + it * 256;
        int r = chunk >> 2, c8 = chunk & 3;
        uint4 v = *(const uint4*)(A + (long)(m0 + r) * 512 + k0 + c8 * 8);
        *(uint4*)&As[r][c8 * 8] = v;
      }
    }
#pragma unroll
    for (int it = 0; it < 4; ++it) {
      int chunk = tid + it * 256;
      int r = chunk >> 5, c4 = chunk & 31;
      float4 v = *(const float4*)(W + (long)(k0 + r) * 512 + n0 + c4 * 4);
      Bs[c4 * 4 + 0][r] = f2bf(v.x);
      Bs[c4 * 4 + 1][r] = f2bf(v.y);
      Bs[c4 * 4 + 2][r] = f2bf(v.z);
      Bs[c4 * 4 + 3][r] = f2bf(v.w);
    }
    __syncthreads();

    bf16x8 af[4], bfr[4];
#pragma unroll
    for (int mi = 0; mi < 4; ++mi)
      af[mi] = *(const bf16x8*)&As[waveM * 64 + mi * 16 + col][quad * 8];
#pragma unroll
    for (int ni = 0; ni < 4; ++ni)
      bfr[ni] = *(const bf16x8*)&Bs[waveN * 64 + ni * 16 + col][quad * 8];
#pragma unroll
    for (int mi = 0; mi < 4; ++mi)
#pragma unroll
      for (int ni = 0; ni < 4; ++ni)
        acc[mi][ni] = __builtin_amdgcn_mfma_f32_16x16x32_bf16(
            af[mi], bfr[ni], acc[mi][ni], 0, 0, 0);
  }

#pragma unroll
  for (int ni = 0; ni < 4; ++ni) {
    const int gn = n0 + waveN * 64 + ni * 16 + col;
    const float bv = bias[gn];
#pragma unroll
    for (int mi = 0; mi < 4; ++mi) {
#pragma unroll
      for (int r = 0; r < 4; ++r) {
        const int gm = m0 + waveM * 64 + mi * 16 + quad * 4 + r;
        const float val = acc[mi][ni][r] + bv;
        if constexpr (HEADS_OUT) {
          const int b_ = gm >> 9, s_ = gm & 511, h_ = gn >> 6, dk_ = gn & 63;
          ((unsigned short*)outv)[(((long)(b_ * 8 + h_)) * 512 + s_) * 64 + dk_] =
              f2bf(val);
        } else {
          ((float*)outv)[(long)gm * 512 + gn] = val;
        }
      }
    }
  }
}

// ---------------------------------------------------------------------------
// attn_sel: per query row, fp32 scores (strictly causal), streaming top-k.
// Identity: top-k(probs) == top-k(scores); rows i<k == keep-all-renormalize.
// Writes normalized weights (8 floats) + indices (8 ints) into the row's own
// q-slot in qh (each thread reads only its own q row -> safe self-overwrite).
// ---------------------------------------------------------------------------
__global__ __launch_bounds__(256) void attn_sel_kernel(
    float* __restrict__ qh, const float* __restrict__ kh,
    const int* __restrict__ kidx_ptr) {
  __shared__ float Ks[128][64];  // 32 KB

  const int bh = blockIdx.y;
  const int i = blockIdx.x * 256 + (int)threadIdx.x;
  const int kidx = min(kidx_ptr[0], 8);

  float* Qrow = qh + ((long)bh * 512 + i) * 64;
  const float* Kb = kh + (long)bh * 512 * 64;

  float q[64];
#pragma unroll
  for (int c = 0; c < 16; ++c)
    *(float4*)&q[c * 4] = *(const float4*)(Qrow + c * 4);

  float topv[8];
  int topi[8];
#pragma unroll
  for (int t = 0; t < 8; ++t) { topv[t] = -1e30f; topi[t] = 0; }
  float kth = -1e30f;

  const int ntiles = (blockIdx.x + 1) * 2;
  for (int t = 0; t < ntiles; ++t) {
    __syncthreads();
#pragma unroll
    for (int it = 0; it < 8; ++it) {
      int chunk = (int)threadIdx.x + it * 256;  // 2048 float4 chunks (128x64)
      int r = chunk >> 4, c4 = chunk & 15;
      *(float4*)&Ks[r][c4 * 4] =
          *(const float4*)(Kb + ((long)(t * 128 + r)) * 64 + c4 * 4);
    }
    __syncthreads();

    const int jmax = min(i - t * 128, 128);  // strictly causal: j < i
    for (int j = 0; j < jmax; ++j) {
      float s0 = 0.f, s1 = 0.f, s2 = 0.f, s3 = 0.f;
#pragma unroll
      for (int c = 0; c < 16; ++c) {
        float4 kv = *(const float4*)&Ks[j][c * 4];  // broadcast read
        s0 = fmaf(q[c * 4 + 0], kv.x, s0);
        s1 = fmaf(q[c * 4 + 1], kv.y, s1);
        s2 = fmaf(q[c * 4 + 2], kv.z, s2);
        s3 = fmaf(q[c * 4 + 3], kv.w, s3);
      }
      const float s = (s0 + s1 + s2 + s3) * 0.125f;  // 1/sqrt(64)
      if (s > kth) {
        float cv = s;
        int ci = t * 128 + j;
#pragma unroll
        for (int u = 0; u < 8; ++u) {
          if (cv > topv[u]) {
            float tv = topv[u]; topv[u] = cv; cv = tv;
            int ti = topi[u]; topi[u] = ci; ci = ti;
          }
        }
#pragma unroll
        for (int u = 0; u < 8; ++u)
          if (u == kidx - 1) kth = topv[u];
      }
    }
  }

  const float m = topv[0];
  float w[8];
  float num = 0.f;
#pragma unroll
  for (int t = 0; t < 8; ++t) {
    const bool valid = (t < kidx) && (topv[t] > -1e29f);
    w[t] = valid ? expf(topv[t] - m) : 0.f;
    num += w[t];
  }
  const float inv = (num > 0.f) ? 1.f / num : 0.f;  // row 0: all-zero weights

#pragma unroll
  for (int t = 0; t < 8; ++t) Qrow[t] = w[t] * inv;
  int* ip = (int*)Qrow;
#pragma unroll
  for (int t = 0; t < 8; ++t) ip[8 + t] = topi[t];
}

// ---------------------------------------------------------------------------
// gather: out_attn[row] = sum_t w_t * vh[idx_t]   (bf16 concat layout)
// ---------------------------------------------------------------------------
__global__ __launch_bounds__(256) void gather_kernel(
    const float* __restrict__ qh_sel, const unsigned short* __restrict__ vh,
    unsigned short* __restrict__ attn) {
  const int row = blockIdx.x * 256 + (int)threadIdx.x;  // [0, 131072)
  const int bh = row >> 9, i = row & 511;
  const int b = bh >> 3, h = bh & 7;

  const float* sel = qh_sel + (long)row * 64;
  const int* ip = (const int*)sel;

  float o[64];
#pragma unroll
  for (int d = 0; d < 64; ++d) o[d] = 0.f;

#pragma unroll
  for (int t = 0; t < 8; ++t) {
    const float w = sel[t];
    if (w != 0.f) {
      const unsigned short* Vrow = vh + ((long)bh * 512 + ip[8 + t]) * 64;
#pragma unroll
      for (int c = 0; c < 8; ++c) {
        uint4 raw = *(const uint4*)(Vrow + c * 8);
        float f[8];
        unpack8(raw, f);
#pragma unroll
        for (int d = 0; d < 8; ++d) o[c * 8 + d] = fmaf(w, f[d], o[c * 8 + d]);
      }
    }
  }

  const long ob = ((long)(b * 512 + i)) * 512 + h * 64;
#pragma unroll
  for (int c = 0; c < 8; ++c) {
    uint4 wv;
    wv.x = (unsigned)f2bf(o[c * 8 + 0]) | ((unsigned)f2bf(o[c * 8 + 1]) << 16);
    wv.y = (unsigned)f2bf(o[c * 8 + 2]) | ((unsigned)f2bf(o[c * 8 + 3]) << 16);
    wv.z = (unsigned)f2bf(o[c * 8 + 4]) | ((unsigned)f2bf(o[c * 8 + 5]) << 16);
    wv.w = (unsigned)f2bf(o[c * 8 + 6]) | ((unsigned)f2bf(o[c * 8 + 7]) << 16);
    *(uint4*)&attn[ob + c * 8] = wv;
  }
}

// ---------------------------------------------------------------------------
extern "C" void kernel_launch(void* const* d_in, const int* in_sizes, int n_in,
                              void* d_out, int out_size, void* d_ws, size_t ws_size,
                              hipStream_t stream) {
  const float* q   = (const float*)d_in[0];
  const float* k   = (const float*)d_in[1];
  const float* v   = (const float*)d_in[2];
  const float* w_q = (const float*)d_in[3];
  const float* b_q = (const float*)d_in[4];
  const float* w_k = (const float*)d_in[5];
  const float* b_k = (const float*)d_in[6];
  const float* w_v = (const float*)d_in[7];
  const float* b_v = (const float*)d_in[8];
  const float* w_o = (const float*)d_in[9];
  const float* b_o = (const float*)d_in[10];
  const int* kidx  = (const int*)d_in[11];

  // workspace (64 MiB): qh fp32 32M | kh fp32 32M; after attn_sel, kh region
  // is reused for vh bf16 (16M) + attn bf16 (16M). Stream order makes it safe.
  const long NE = (long)Bn * Hn * Sn * DKn;  // 8388608
  float* qh = (float*)d_ws;
  float* kh = qh + NE;
  unsigned short* vh   = (unsigned short*)kh;
  unsigned short* attn = vh + NE;

  const dim3 gg(128, 4), bb(256);
  gemm_f16split_kernel<<<gg, bb, 0, stream>>>(q, w_q, b_q, qh);
  gemm_f16split_kernel<<<gg, bb, 0, stream>>>(k, w_k, b_k, kh);
  attn_sel_kernel<<<dim3(2, 256), bb, 0, stream>>>(qh, kh, kidx);
  gemm_kernel<false, true><<<gg, bb, 0, stream>>>(v, w_v, b_v, vh);
  gather_kernel<<<512, bb, 0, stream>>>(qh, vh, attn);
  gemm_kernel<true, false><<<gg, bb, 0, stream>>>(attn, w_o, b_o, (float*)d_out);
}

// Round 4
// 829.613 us; speedup vs baseline: 1.0948x; 1.0948x over previous
//
#include <hip/hip_runtime.h>

// Problem constants (B,S,D,H fixed by reference)
constexpr int Bn = 32, Sn = 512, Dn = 512, Hn = 8, DKn = 64;

typedef __attribute__((ext_vector_type(8))) short bf16x8;
typedef __attribute__((ext_vector_type(8))) _Float16 f16x8;
typedef __attribute__((ext_vector_type(4))) _Float16 f16x4;
typedef __attribute__((ext_vector_type(4))) float f32x4;

#define DEV_INLINE __device__ __forceinline__

DEV_INLINE float bf2f(unsigned int u) { return __uint_as_float(u << 16); }

DEV_INLINE unsigned short f2bf(float f) {
  unsigned int u = __float_as_uint(f);
  u += 0x7fffu + ((u >> 16) & 1u);   // round-to-nearest-even; inputs finite
  return (unsigned short)(u >> 16);
}

DEV_INLINE void unpack8(const uint4 r, float* o) {
  o[0] = bf2f(r.x & 0xffffu); o[1] = bf2f(r.x >> 16);
  o[2] = bf2f(r.y & 0xffffu); o[3] = bf2f(r.y >> 16);
  o[4] = bf2f(r.z & 0xffffu); o[5] = bf2f(r.z >> 16);
  o[6] = bf2f(r.w & 0xffffu); o[7] = bf2f(r.w >> 16);
}

struct F16Pair { _Float16 hi, lo; };
DEV_INLINE F16Pair splitf(float x) {
  F16Pair p;
  p.hi = (_Float16)x;
  p.lo = (_Float16)(x - (float)p.hi);
  return p;
}

// ---------------------------------------------------------------------------
// fp32-accurate GEMM via f16x2 split MFMA (Markidis): out = A[M,512]*W + b.
// W pre-scaled by 64 at staging (keeps lo normal); epilogue rescales by 1/64.
// OUT_MODE 0: fp32 heads [b,h,s,dk].
// OUT_MODE 1: f16 hi/lo heads — row = (b*8+h)*512+s, 128 f16: [64 hi | 64 lo]
//             (feeds attn_sel's B-fragment loads with zero conversion cost).
// ---------------------------------------------------------------------------
template <int OUT_MODE>
__global__ __launch_bounds__(256) void gemm_f16split_kernel(
    const float* __restrict__ A, const float* __restrict__ W,
    const float* __restrict__ bias, void* __restrict__ outv) {
  __shared__ _Float16 Ash[128][48], Asl[128][48];
  __shared__ _Float16 Bsh[128][48], Bsl[128][48];  // [n][k] transposed

  const int m0 = blockIdx.x * 128, n0 = blockIdx.y * 128;
  const int tid  = threadIdx.x;
  const int lane = tid & 63, wave = tid >> 6;
  const int waveM = wave >> 1, waveN = wave & 1;
  const int col = lane & 15, quad = lane >> 4;

  f32x4 acc[4][4];
#pragma unroll
  for (int mi = 0; mi < 4; ++mi)
#pragma unroll
    for (int ni = 0; ni < 4; ++ni) acc[mi][ni] = (f32x4){0.f, 0.f, 0.f, 0.f};

  for (int k0 = 0; k0 < 512; k0 += 32) {
    __syncthreads();
#pragma unroll
    for (int it = 0; it < 4; ++it) {
      int chunk = tid + it * 256;            // 1024 float4 chunks (128x32)
      int r = chunk >> 3, c4 = chunk & 7;
      float4 v = *(const float4*)(A + (long)(m0 + r) * 512 + k0 + c4 * 4);
      F16Pair p0 = splitf(v.x), p1 = splitf(v.y),
              p2 = splitf(v.z), p3 = splitf(v.w);
      f16x4 hv = {p0.hi, p1.hi, p2.hi, p3.hi};
      f16x4 lv = {p0.lo, p1.lo, p2.lo, p3.lo};
      *(f16x4*)&Ash[r][c4 * 4] = hv;
      *(f16x4*)&Asl[r][c4 * 4] = lv;
    }
#pragma unroll
    for (int it = 0; it < 4; ++it) {
      int chunk = tid + it * 256;            // 32 k-rows x 32 n-chunks
      int r = chunk >> 5, c4 = chunk & 31;
      float4 v = *(const float4*)(W + (long)(k0 + r) * 512 + n0 + c4 * 4);
      F16Pair p0 = splitf(v.x * 64.f), p1 = splitf(v.y * 64.f),
              p2 = splitf(v.z * 64.f), p3 = splitf(v.w * 64.f);
      Bsh[c4 * 4 + 0][r] = p0.hi; Bsl[c4 * 4 + 0][r] = p0.lo;
      Bsh[c4 * 4 + 1][r] = p1.hi; Bsl[c4 * 4 + 1][r] = p1.lo;
      Bsh[c4 * 4 + 2][r] = p2.hi; Bsl[c4 * 4 + 2][r] = p2.lo;
      Bsh[c4 * 4 + 3][r] = p3.hi; Bsl[c4 * 4 + 3][r] = p3.lo;
    }
    __syncthreads();

    f16x8 ah[4], al[4], bh[4], bl[4];
#pragma unroll
    for (int mi = 0; mi < 4; ++mi) {
      ah[mi] = *(const f16x8*)&Ash[waveM * 64 + mi * 16 + col][quad * 8];
      al[mi] = *(const f16x8*)&Asl[waveM * 64 + mi * 16 + col][quad * 8];
    }
#pragma unroll
    for (int ni = 0; ni < 4; ++ni) {
      bh[ni] = *(const f16x8*)&Bsh[waveN * 64 + ni * 16 + col][quad * 8];
      bl[ni] = *(const f16x8*)&Bsl[waveN * 64 + ni * 16 + col][quad * 8];
    }
#pragma unroll
    for (int mi = 0; mi < 4; ++mi)
#pragma unroll
      for (int ni = 0; ni < 4; ++ni) {
        acc[mi][ni] = __builtin_amdgcn_mfma_f32_16x16x32_f16(
            ah[mi], bl[ni], acc[mi][ni], 0, 0, 0);
        acc[mi][ni] = __builtin_amdgcn_mfma_f32_16x16x32_f16(
            al[mi], bh[ni], acc[mi][ni], 0, 0, 0);
        acc[mi][ni] = __builtin_amdgcn_mfma_f32_16x16x32_f16(
            ah[mi], bh[ni], acc[mi][ni], 0, 0, 0);
      }
  }

  // C/D layout: col=lane&15, row=quad*4+reg (m89/m91-verified)
#pragma unroll
  for (int ni = 0; ni < 4; ++ni) {
    const int gn = n0 + waveN * 64 + ni * 16 + col;
    const float bv = bias[gn];
    const int h_ = gn >> 6, dk_ = gn & 63;
#pragma unroll
    for (int mi = 0; mi < 4; ++mi) {
#pragma unroll
      for (int r = 0; r < 4; ++r) {
        const int gm = m0 + waveM * 64 + mi * 16 + quad * 4 + r;
        const int b_ = gm >> 9, s_ = gm & 511;
        const long row = (long)(b_ * 8 + h_) * 512 + s_;
        const float val = acc[mi][ni][r] * 0.015625f + bv;
        if constexpr (OUT_MODE == 0) {
          ((float*)outv)[row * 64 + dk_] = val;
        } else {
          F16Pair p = splitf(val);
          ((_Float16*)outv)[row * 128 + dk_]      = p.hi;
          ((_Float16*)outv)[row * 128 + 64 + dk_] = p.lo;
        }
      }
    }
  }
}

// ---------------------------------------------------------------------------
// bf16 MFMA GEMM (for v-projection and out-projection; continuous-error path)
// ---------------------------------------------------------------------------
template <bool A_IS_BF16, bool HEADS_OUT>
__global__ __launch_bounds__(256) void gemm_kernel(
    const void* __restrict__ Av, const float* __restrict__ W,
    const float* __restrict__ bias, void* __restrict__ outv) {
  __shared__ unsigned short As[128][48];
  __shared__ unsigned short Bs[128][48];  // [n][k]

  const int m0 = blockIdx.x * 128, n0 = blockIdx.y * 128;
  const int tid  = threadIdx.x;
  const int lane = tid & 63, wave = tid >> 6;
  const int waveM = wave >> 1, waveN = wave & 1;
  const int col = lane & 15, quad = lane >> 4;

  f32x4 acc[4][4];
#pragma unroll
  for (int mi = 0; mi < 4; ++mi)
#pragma unroll
    for (int ni = 0; ni < 4; ++ni) acc[mi][ni] = (f32x4){0.f, 0.f, 0.f, 0.f};

  for (int k0 = 0; k0 < 512; k0 += 32) {
    __syncthreads();
    if constexpr (!A_IS_BF16) {
      const float* A = (const float*)Av;
#pragma unroll
      for (int it = 0; it < 4; ++it) {
        int chunk = tid + it * 256;
        int r = chunk >> 3, c4 = chunk & 7;
        float4 v = *(const float4*)(A + (long)(m0 + r) * 512 + k0 + c4 * 4);
        ushort4 w;
        w.x = f2bf(v.x); w.y = f2bf(v.y); w.z = f2bf(v.z); w.w = f2bf(v.w);
        *(ushort4*)&As[r][c4 * 4] = w;
      }
    } else {
      const unsigned short* A = (const unsigned short*)Av;
#pragma unroll
      for (int it = 0; it < 2; ++it) {
        int chunk = tid + it * 256;
        int r = chunk >> 2, c8 = chunk & 3;
        uint4 v = *(const uint4*)(A + (long)(m0 + r) * 512 + k0 + c8 * 8);
        *(uint4*)&As[r][c8 * 8] = v;
      }
    }
#pragma unroll
    for (int it = 0; it < 4; ++it) {
      int chunk = tid + it * 256;
      int r = chunk >> 5, c4 = chunk & 31;
      float4 v = *(const float4*)(W + (long)(k0 + r) * 512 + n0 + c4 * 4);
      Bs[c4 * 4 + 0][r] = f2bf(v.x);
      Bs[c4 * 4 + 1][r] = f2bf(v.y);
      Bs[c4 * 4 + 2][r] = f2bf(v.z);
      Bs[c4 * 4 + 3][r] = f2bf(v.w);
    }
    __syncthreads();

    bf16x8 af[4], bfr[4];
#pragma unroll
    for (int mi = 0; mi < 4; ++mi)
      af[mi] = *(const bf16x8*)&As[waveM * 64 + mi * 16 + col][quad * 8];
#pragma unroll
    for (int ni = 0; ni < 4; ++ni)
      bfr[ni] = *(const bf16x8*)&Bs[waveN * 64 + ni * 16 + col][quad * 8];
#pragma unroll
    for (int mi = 0; mi < 4; ++mi)
#pragma unroll
      for (int ni = 0; ni < 4; ++ni)
        acc[mi][ni] = __builtin_amdgcn_mfma_f32_16x16x32_bf16(
            af[mi], bfr[ni], acc[mi][ni], 0, 0, 0);
  }

#pragma unroll
  for (int ni = 0; ni < 4; ++ni) {
    const int gn = n0 + waveN * 64 + ni * 16 + col;
    const float bv = bias[gn];
#pragma unroll
    for (int mi = 0; mi < 4; ++mi) {
#pragma unroll
      for (int r = 0; r < 4; ++r) {
        const int gm = m0 + waveM * 64 + mi * 16 + quad * 4 + r;
        const float val = acc[mi][ni][r] + bv;
        if constexpr (HEADS_OUT) {
          const int b_ = gm >> 9, s_ = gm & 511, h_ = gn >> 6, dk_ = gn & 63;
          ((unsigned short*)outv)[(((long)(b_ * 8 + h_)) * 512 + s_) * 64 + dk_] =
              f2bf(val);
        } else {
          ((float*)outv)[(long)gm * 512 + gn] = val;
        }
      }
    }
  }
}

// ---------------------------------------------------------------------------
// attn_sel (MFMA): block = (i-tile of 128 rows, bh), 128 threads (2 waves).
// Per 64-col j-tile: compute 128x64 fp32-accurate scores via 4-term f16-split
// MFMA (hi*hi + hi*lo + lo*hi + lo*lo ~ 2^-22 accuracy), stage to LDS
// [128][65] (stride 65 -> 2 lanes/bank = free), then 128 threads stream
// top-8 over their row. Scores kept UNSCALED (selection is monotone); the
// 1/sqrt(64)=0.125 scale is applied (exactly, pow2) at the exp step.
// A-frags: q fp32 -> hi/lo in regs once per block. B-frags: khl pre-split.
// Writes normalized weights (8 f32) + indices (8 i32) into own q row (safe:
// block reads those q rows only at entry, before any write).
// ---------------------------------------------------------------------------
__global__ __launch_bounds__(128) void attn_sel_kernel(
    float* __restrict__ qh, const _Float16* __restrict__ khl,
    const int* __restrict__ kidx_ptr) {
  __shared__ float Ss[128][65];  // 33.3 KB

  const int tid = threadIdx.x;
  const int lane = tid & 63, wave = tid >> 6;
  const int col16 = lane & 15, quad = lane >> 4;
  const int bh = blockIdx.y, ti = blockIdx.x;
  const int i0 = ti * 128;
  const int kidx = min(kidx_ptr[0], 8);

  const float* Qb = qh + (long)bh * 512 * 64;
  const _Float16* Kb = khl + (long)bh * 512 * 128;

  // A fragments: rows i0 + wave*64 + mi*16 + col16, k = c*32 + quad*8
  f16x8 ah[4][2], al[4][2];
#pragma unroll
  for (int mi = 0; mi < 4; ++mi)
#pragma unroll
    for (int c = 0; c < 2; ++c) {
      const float* p =
          Qb + (long)(i0 + wave * 64 + mi * 16 + col16) * 64 + c * 32 + quad * 8;
      float4 x0 = *(const float4*)p, x1 = *(const float4*)(p + 4);
      float xs[8] = {x0.x, x0.y, x0.z, x0.w, x1.x, x1.y, x1.z, x1.w};
      f16x8 hv, lv;
#pragma unroll
      for (int e = 0; e < 8; ++e) {
        F16Pair pr = splitf(xs[e]);
        hv[e] = pr.hi; lv[e] = pr.lo;
      }
      ah[mi][c] = hv; al[mi][c] = lv;
    }

  float topv[8];
  int topi[8];
#pragma unroll
  for (int t = 0; t < 8; ++t) { topv[t] = -1e30f; topi[t] = 0; }
  float kth = -1e30f;

  const int ntiles = 2 * ti + 2;
  for (int t = 0; t < ntiles; ++t) {
    if (t > 0) __syncthreads();  // prior selection done reading Ss

    // ---- compute 128x64 score tile into LDS ----
    const _Float16* Kt = Kb + (long)t * 64 * 128;
#pragma unroll
    for (int ni = 0; ni < 4; ++ni) {
      f16x8 bhf[2], blf[2];
#pragma unroll
      for (int c = 0; c < 2; ++c) {
        const _Float16* p = Kt + (long)(ni * 16 + col16) * 128 + c * 32 + quad * 8;
        bhf[c] = *(const f16x8*)p;
        blf[c] = *(const f16x8*)(p + 64);
      }
#pragma unroll
      for (int mi = 0; mi < 4; ++mi) {
        f32x4 a = (f32x4){0.f, 0.f, 0.f, 0.f};
#pragma unroll
        for (int c = 0; c < 2; ++c) {
          a = __builtin_amdgcn_mfma_f32_16x16x32_f16(al[mi][c], blf[c], a, 0, 0, 0);
          a = __builtin_amdgcn_mfma_f32_16x16x32_f16(ah[mi][c], blf[c], a, 0, 0, 0);
          a = __builtin_amdgcn_mfma_f32_16x16x32_f16(al[mi][c], bhf[c], a, 0, 0, 0);
          a = __builtin_amdgcn_mfma_f32_16x16x32_f16(ah[mi][c], bhf[c], a, 0, 0, 0);
        }
        const int row_l = wave * 64 + mi * 16 + quad * 4;
        const int col_l = ni * 16 + col16;
#pragma unroll
        for (int r = 0; r < 4; ++r) Ss[row_l + r][col_l] = a[r];
      }
    }
    __syncthreads();

    // ---- selection scan: thread tid = local row ----
    const int i = i0 + tid;
    const int jmax = min(i - t * 64, 64);  // strictly causal: j < i
    for (int c = 0; c < jmax; ++c) {
      const float s = Ss[tid][c];
      if (s > kth) {
        float cv = s;
        int ci = t * 64 + c;
#pragma unroll
        for (int u = 0; u < 8; ++u) {
          if (cv > topv[u]) {
            float tv = topv[u]; topv[u] = cv; cv = tv;
            int tix = topi[u]; topi[u] = ci; ci = tix;
          }
        }
#pragma unroll
        for (int u = 0; u < 8; ++u)
          if (u == kidx - 1) kth = topv[u];
      }
    }
  }

  // ---- weights (scale applied here, exact pow2) + write to own q row ----
  const float m = topv[0];
  float w[8];
  float num = 0.f;
#pragma unroll
  for (int t = 0; t < 8; ++t) {
    const bool valid = (t < kidx) && (topv[t] > -1e29f);
    w[t] = valid ? expf((topv[t] - m) * 0.125f) : 0.f;
    num += w[t];
  }
  const float inv = (num > 0.f) ? 1.f / num : 0.f;  // row 0: all-zero weights

  float* Qrow = qh + ((long)bh * 512 + i0 + tid) * 64;
#pragma unroll
  for (int t = 0; t < 8; ++t) Qrow[t] = w[t] * inv;
  int* ip = (int*)Qrow;
#pragma unroll
  for (int t = 0; t < 8; ++t) ip[8 + t] = topi[t];
}

// ---------------------------------------------------------------------------
// gather: out_attn[row] = sum_t w_t * vh[idx_t]   (bf16 concat layout)
// ---------------------------------------------------------------------------
__global__ __launch_bounds__(256) void gather_kernel(
    const float* __restrict__ qh_sel, const unsigned short* __restrict__ vh,
    unsigned short* __restrict__ attn) {
  const int row = blockIdx.x * 256 + (int)threadIdx.x;  // [0, 131072)
  const int bh = row >> 9, i = row & 511;
  const int b = bh >> 3, h = bh & 7;

  const float* sel = qh_sel + (long)row * 64;
  const int* ip = (const int*)sel;

  float o[64];
#pragma unroll
  for (int d = 0; d < 64; ++d) o[d] = 0.f;

#pragma unroll
  for (int t = 0; t < 8; ++t) {
    const float w = sel[t];
    if (w != 0.f) {
      const unsigned short* Vrow = vh + ((long)bh * 512 + ip[8 + t]) * 64;
#pragma unroll
      for (int c = 0; c < 8; ++c) {
        uint4 raw = *(const uint4*)(Vrow + c * 8);
        float f[8];
        unpack8(raw, f);
#pragma unroll
        for (int d = 0; d < 8; ++d) o[c * 8 + d] = fmaf(w, f[d], o[c * 8 + d]);
      }
    }
  }

  const long ob = ((long)(b * 512 + i)) * 512 + h * 64;
#pragma unroll
  for (int c = 0; c < 8; ++c) {
    uint4 wv;
    wv.x = (unsigned)f2bf(o[c * 8 + 0]) | ((unsigned)f2bf(o[c * 8 + 1]) << 16);
    wv.y = (unsigned)f2bf(o[c * 8 + 2]) | ((unsigned)f2bf(o[c * 8 + 3]) << 16);
    wv.z = (unsigned)f2bf(o[c * 8 + 4]) | ((unsigned)f2bf(o[c * 8 + 5]) << 16);
    wv.w = (unsigned)f2bf(o[c * 8 + 6]) | ((unsigned)f2bf(o[c * 8 + 7]) << 16);
    *(uint4*)&attn[ob + c * 8] = wv;
  }
}

// ---------------------------------------------------------------------------
extern "C" void kernel_launch(void* const* d_in, const int* in_sizes, int n_in,
                              void* d_out, int out_size, void* d_ws, size_t ws_size,
                              hipStream_t stream) {
  const float* q   = (const float*)d_in[0];
  const float* k   = (const float*)d_in[1];
  const float* v   = (const float*)d_in[2];
  const float* w_q = (const float*)d_in[3];
  const float* b_q = (const float*)d_in[4];
  const float* w_k = (const float*)d_in[5];
  const float* b_k = (const float*)d_in[6];
  const float* w_v = (const float*)d_in[7];
  const float* b_v = (const float*)d_in[8];
  const float* w_o = (const float*)d_in[9];
  const float* b_o = (const float*)d_in[10];
  const int* kidx  = (const int*)d_in[11];

  // workspace (64 MiB): qh fp32 32M (also holds sel output) | khl f16-hilo
  // 32M. After attn_sel consumes khl, that region is reused for vh bf16
  // (16M) + attn bf16 (16M). Stream order makes the overlay safe.
  const long NE = (long)Bn * Hn * Sn * DKn;  // 8388608
  float* qh = (float*)d_ws;
  _Float16* khl = (_Float16*)(qh + NE);      // 131072 rows x 128 f16
  unsigned short* vh   = (unsigned short*)khl;
  unsigned short* attn = vh + NE;

  const dim3 gg(128, 4), bb(256);
  gemm_f16split_kernel<0><<<gg, bb, 0, stream>>>(q, w_q, b_q, qh);
  gemm_f16split_kernel<1><<<gg, bb, 0, stream>>>(k, w_k, b_k, khl);
  attn_sel_kernel<<<dim3(4, 256), dim3(128), 0, stream>>>(qh, khl, kidx);
  gemm_kernel<false, true><<<gg, bb, 0, stream>>>(v, w_v, b_v, vh);
  gather_kernel<<<512, bb, 0, stream>>>(qh, vh, attn);
  gemm_kernel<true, false><<<gg, bb, 0, stream>>>(attn, w_o, b_o, (float*)d_out);
}